// Round 1
// baseline (27194.196 us; speedup 1.0000x reference)
//
#include <hip/hip_runtime.h>

// ULSTM layer: S=1024, B=32, IN=1024, H=1024
// Strategy:
//  - prep: permute+transpose weights to bf16 (N,K) layout, fold biases
//  - gemm_in: Y[s*b, 5120] = X @ W_iozfux + folded bias (permuted cols, bf16 out)
//  - ulstm_rec: cooperative persistent kernel, 64 blocks x 256 thr,
//    2 hand-rolled grid barriers per step, MFMA 16x16x32 bf16.

typedef unsigned short u16;
typedef __attribute__((ext_vector_type(4))) float f32x4;
typedef __attribute__((ext_vector_type(8))) short s16x8;     // 8 bf16 (MFMA A/B frag)
typedef __attribute__((ext_vector_type(8))) unsigned short u16x8;

#define SEQ   1024
#define BATCH 32
#define HDIM  1024
#define GBLK  64          // persistent blocks; each owns 16 hidden cols

__device__ __forceinline__ u16 f2bf(float f) {
    unsigned u = __builtin_bit_cast(unsigned, f);
    return (u16)((u + 0x7FFFu + ((u >> 16) & 1u)) >> 16);   // RNE
}
__device__ __forceinline__ float bf2f(u16 h) {
    return __builtin_bit_cast(float, (unsigned)h << 16);
}

// ---------------------------------------------------------------- prep kernels
// permuted column p: g = p/80, r = p%80, gate = r>>4 (0..4 = i,o,z,f,u), j = r&15
// hidden index n = 16g + j; original 5H col = gate<4 ? gate*H+n : 4H+n
__global__ void prep_w0(const float* __restrict__ W, const float* __restrict__ b_ux,
                        const float* __restrict__ b_h, const float* __restrict__ b_um,
                        u16* __restrict__ W0p, float* __restrict__ biasp) {
    int p = blockIdx.x;                       // 5120
    int g = p / 80, r = p % 80, gate = r >> 4, j = r & 15;
    int n = 16 * g + j;
    int c = (gate < 4) ? gate * 1024 + n : 4096 + n;
    for (int k = threadIdx.x; k < 1024; k += 256)
        W0p[(long)p * 1024 + k] = f2bf(W[(long)k * 5120 + c]);
    if (threadIdx.x == 0)
        biasp[p] = b_ux[c] + ((gate < 4) ? b_h[gate * 1024 + n] : b_um[n]);
}

__global__ void prep_w1(const float* __restrict__ W, u16* __restrict__ W1p) {
    int qq = blockIdx.x;                      // 4096
    int g = qq >> 6, r = qq & 63, gate = r >> 4, j = r & 15;
    int n = 16 * g + j;
    int c = gate * 1024 + n;
    for (int k = threadIdx.x; k < 1024; k += 256)
        W1p[(long)qq * 1024 + k] = f2bf(W[(long)k * 4096 + c]);
}

__global__ void prep_w2(const float* __restrict__ W, u16* __restrict__ W2p) {
    int n = blockIdx.x;                       // 1024
    for (int k = threadIdx.x; k < 1024; k += 256)
        W2p[(long)n * 1024 + k] = f2bf(W[(long)k * 1024 + n]);
}

// ---------------------------------------------------------- input projection
// C = X(32768x1024) @ W0p^T  (W0p is (5120 x 1024) = B^T), + biasp, out bf16
// block: 128x64 tile, 256 thr (4 waves); wave w -> rows [32w,32w+32), all 64 cols
__global__ void __launch_bounds__(256) gemm_in(const float* __restrict__ X,
                                               const u16* __restrict__ W0p,
                                               const float* __restrict__ biasp,
                                               u16* __restrict__ Y) {
    __shared__ u16 As[128 * 40];   // stride 40 elems (80B, 16B-aligned, 2-way banks)
    __shared__ u16 Bs[64 * 40];
    const int tid = threadIdx.x, lane = tid & 63, w = tid >> 6;
    const int m = lane & 15, q = lane >> 4;
    const int m0 = blockIdx.y * 128, n0 = blockIdx.x * 64;

    f32x4 acc[2][4];
#pragma unroll
    for (int a = 0; a < 2; ++a)
#pragma unroll
        for (int b = 0; b < 4; ++b) acc[a][b] = (f32x4){0.f, 0.f, 0.f, 0.f};

    const int ar = tid >> 1, as = (tid & 1) * 16;   // A stage: row, k-seg(16)
    const int br = tid >> 2, bs = (tid & 3) * 8;    // B stage: row, k-seg(8)

    for (int k0 = 0; k0 < 1024; k0 += 32) {
        const float* xp = X + (long)(m0 + ar) * 1024 + k0 + as;
        float4 x0 = *(const float4*)(xp);
        float4 x1 = *(const float4*)(xp + 4);
        float4 x2 = *(const float4*)(xp + 8);
        float4 x3 = *(const float4*)(xp + 12);
        u16x8 pa, pb;
        pa[0]=f2bf(x0.x); pa[1]=f2bf(x0.y); pa[2]=f2bf(x0.z); pa[3]=f2bf(x0.w);
        pa[4]=f2bf(x1.x); pa[5]=f2bf(x1.y); pa[6]=f2bf(x1.z); pa[7]=f2bf(x1.w);
        pb[0]=f2bf(x2.x); pb[1]=f2bf(x2.y); pb[2]=f2bf(x2.z); pb[3]=f2bf(x2.w);
        pb[4]=f2bf(x3.x); pb[5]=f2bf(x3.y); pb[6]=f2bf(x3.z); pb[7]=f2bf(x3.w);
        u16x8 bv = *(const u16x8*)(W0p + (long)(n0 + br) * 1024 + k0 + bs);

        *(u16x8*)&As[ar * 40 + as]     = pa;
        *(u16x8*)&As[ar * 40 + as + 8] = pb;
        *(u16x8*)&Bs[br * 40 + bs]     = bv;
        __syncthreads();

        s16x8 a0 = *(const s16x8*)&As[(w * 32 + m) * 40 + q * 8];
        s16x8 a1 = *(const s16x8*)&As[(w * 32 + 16 + m) * 40 + q * 8];
#pragma unroll
        for (int nt = 0; nt < 4; ++nt) {
            s16x8 b = *(const s16x8*)&Bs[(nt * 16 + m) * 40 + q * 8];
            acc[0][nt] = __builtin_amdgcn_mfma_f32_16x16x32_bf16(a0, b, acc[0][nt], 0, 0, 0);
            acc[1][nt] = __builtin_amdgcn_mfma_f32_16x16x32_bf16(a1, b, acc[1][nt], 0, 0, 0);
        }
        __syncthreads();
    }
    // epilogue: D layout col = lane&15, row = q*4 + r
#pragma unroll
    for (int mt = 0; mt < 2; ++mt)
#pragma unroll
        for (int nt = 0; nt < 4; ++nt)
#pragma unroll
            for (int r = 0; r < 4; ++r) {
                int row = m0 + w * 32 + mt * 16 + q * 4 + r;
                int col = n0 + nt * 16 + m;
                Y[(long)row * 5120 + col] = f2bf(acc[mt][nt][r] + biasp[col]);
            }
}

// -------------------------------------------------------------- grid barrier
__device__ __forceinline__ void gridbar(unsigned* cnt, unsigned target) {
    __syncthreads();
    if (threadIdx.x == 0) {
        __hip_atomic_fetch_add(cnt, 1u, __ATOMIC_RELEASE, __HIP_MEMORY_SCOPE_AGENT);
        while (__hip_atomic_load(cnt, __ATOMIC_RELAXED, __HIP_MEMORY_SCOPE_AGENT) < target)
            __builtin_amdgcn_s_sleep(2);
        (void)__hip_atomic_load(cnt, __ATOMIC_ACQUIRE, __HIP_MEMORY_SCOPE_AGENT);
    }
    __syncthreads();
}

// ------------------------------------------------------------- recurrence
// block g owns hidden cols [16g,16g+16); gemm1 cols = W1p rows [64g,64g+64)
// wave w (0..3) -> gate w (i,o,z,f); phase2: waves 0,1 -> M-tiles of gemm2.
__global__ void __launch_bounds__(256) ulstm_rec(const u16* __restrict__ W1p,
                                                 const u16* __restrict__ W2p,
                                                 const u16* __restrict__ Y,
                                                 u16* h_buf, u16* v_buf,
                                                 float* __restrict__ out,
                                                 unsigned* cnt) {
    __shared__ u16 stage[32 * 1032];        // h (phase1) / v (phase2), stride 1032
    __shared__ float gl[4][32][16];         // i,o,z,f
    __shared__ float c_l[32][16], ct_l[32][16];

    const int g = blockIdx.x, tid = threadIdx.x, lane = tid & 63, w = tid >> 6;
    const int m = lane & 15, q = lane >> 4;

    // init: c = ct = 0, h = 0 (own slice)
    for (int i = tid; i < 512; i += 256) {
        int row = i >> 4, col = i & 15;
        c_l[row][col] = 0.f; ct_l[row][col] = 0.f;
        h_buf[row * 1024 + g * 16 + col] = 0;
    }
    unsigned target = 0;
    gridbar(cnt, target += GBLK);

    for (int t = 0; t < SEQ; ++t) {
        // ---- stage h into LDS (coalesced)
        for (int cch = tid; cch < 4096; cch += 256) {
            int r = cch >> 7, kc = cch & 127;
            *(u16x8*)&stage[r * 1032 + kc * 8] = *(const u16x8*)&h_buf[r * 1024 + kc * 8];
        }
        __syncthreads();

        // ---- gemm1: preact[32 x 16] for gate w
        f32x4 acc0 = (f32x4){0.f,0.f,0.f,0.f}, acc1 = (f32x4){0.f,0.f,0.f,0.f};
        {
            const int brow = g * 64 + w * 16 + m;
            const u16* wp = W1p + (long)brow * 1024;
#pragma unroll 4
            for (int kc = 0; kc < 32; ++kc) {
                int k0 = kc * 32 + q * 8;
                s16x8 a0 = *(const s16x8*)&stage[m * 1032 + k0];
                s16x8 a1 = *(const s16x8*)&stage[(16 + m) * 1032 + k0];
                s16x8 b  = *(const s16x8*)&wp[k0];
                acc0 = __builtin_amdgcn_mfma_f32_16x16x32_bf16(a0, b, acc0, 0, 0, 0);
                acc1 = __builtin_amdgcn_mfma_f32_16x16x32_bf16(a1, b, acc1, 0, 0, 0);
            }
        }
        const long ybase = (long)t * 32 * 5120;
#pragma unroll
        for (int r = 0; r < 4; ++r) {
            int row0 = q * 4 + r, row1 = row0 + 16;
            float p0 = acc0[r] + bf2f(Y[ybase + (long)row0 * 5120 + g * 80 + w * 16 + m]);
            float p1 = acc1[r] + bf2f(Y[ybase + (long)row1 * 5120 + g * 80 + w * 16 + m]);
            float g0 = 1.f / (1.f + __expf(-p0));
            float g1 = 1.f / (1.f + __expf(-p1));
            gl[w][row0][m] = g0;
            gl[w][row1][m] = g1;
            if (w == 2) {       // z-gate: publish v = sigmoid(z) * tanh(c_prev)
                v_buf[row0 * 1024 + g * 16 + m] = f2bf(g0 * ct_l[row0][m]);
                v_buf[row1 * 1024 + g * 16 + m] = f2bf(g1 * ct_l[row1][m]);
            }
        }
        gridbar(cnt, target += GBLK);       // v published grid-wide

        // ---- stage v into LDS
        for (int cch = tid; cch < 4096; cch += 256) {
            int r = cch >> 7, kc = cch & 127;
            *(u16x8*)&stage[r * 1032 + kc * 8] = *(const u16x8*)&v_buf[r * 1024 + kc * 8];
        }
        __syncthreads();

        // ---- gemm2 + state update (waves 0,1)
        if (w < 2) {
            f32x4 acc = (f32x4){0.f,0.f,0.f,0.f};
            const u16* wp = W2p + (long)(g * 16 + m) * 1024;
#pragma unroll 4
            for (int kc = 0; kc < 32; ++kc) {
                int k0 = kc * 32 + q * 8;
                s16x8 a = *(const s16x8*)&stage[(w * 16 + m) * 1032 + k0];
                s16x8 b = *(const s16x8*)&wp[k0];
                acc = __builtin_amdgcn_mfma_f32_16x16x32_bf16(a, b, acc, 0, 0, 0);
            }
#pragma unroll
            for (int r = 0; r < 4; ++r) {
                int row = w * 16 + q * 4 + r;
                float up = acc[r] + bf2f(Y[ybase + (long)row * 5120 + g * 80 + 64 + m]);
                float eu = __expf(2.f * up);
                float u = 1.f - 2.f / (eu + 1.f);           // tanh
                float iv = gl[0][row][m], ov = gl[1][row][m], fv = gl[3][row][m];
                float cv = c_l[row][m];
                float cn = iv * u + fv * cv;
                float ec = __expf(2.f * cn);
                float ctn = 1.f - 2.f / (ec + 1.f);
                float hn = ov * ctn;
                c_l[row][m] = cn;
                ct_l[row][m] = ctn;
                h_buf[row * 1024 + g * 16 + m] = f2bf(hn);
                out[(long)(t * 32 + row) * 1024 + g * 16 + m] = hn;
                if (t == SEQ - 1) {
                    out[33554432l + row * 1024 + g * 16 + m] = hn;          // h_n
                    out[33554432l + 32768 + row * 1024 + g * 16 + m] = cn;  // c_n
                }
            }
        }
        gridbar(cnt, target += GBLK);       // h published grid-wide
    }
}

// ---------------------------------------------------------------------- host
extern "C" void kernel_launch(void* const* d_in, const int* in_sizes, int n_in,
                              void* d_out, int out_size, void* d_ws, size_t ws_size,
                              hipStream_t stream) {
    (void)in_sizes; (void)n_in; (void)out_size; (void)ws_size;
    const float* X  = (const float*)d_in[0];
    const float* W0 = (const float*)d_in[1];
    const float* b0 = (const float*)d_in[2];
    const float* W1 = (const float*)d_in[3];
    const float* b1 = (const float*)d_in[4];
    const float* W2 = (const float*)d_in[5];
    const float* b2 = (const float*)d_in[6];
    float* out = (float*)d_out;
    char* ws = (char*)d_ws;

    u16*   Y     = (u16*)(ws);                      // 32768*5120*2 = 335,544,320
    u16*   W0p   = (u16*)(ws + 335544320l);         // 10,485,760
    u16*   W1p   = (u16*)(ws + 346030080l);         // 8,388,608
    u16*   W2p   = (u16*)(ws + 354418688l);         // 2,097,152
    float* biasp = (float*)(ws + 356515840l);       // 20,480
    u16*   h_buf = (u16*)(ws + 356536320l);         // 65,536
    u16*   v_buf = (u16*)(ws + 356601856l);         // 65,536
    unsigned* cnt = (unsigned*)(ws + 356667392l);   // 4

    hipMemsetAsync(cnt, 0, 4, stream);
    prep_w0<<<5120, 256, 0, stream>>>(W0, b0, b1, b2, W0p, biasp);
    prep_w1<<<4096, 256, 0, stream>>>(W1, W1p);
    prep_w2<<<1024, 256, 0, stream>>>(W2, W2p);
    gemm_in<<<dim3(80, 256), 256, 0, stream>>>(X, W0p, biasp, Y);

    void* args[] = { (void*)&W1p, (void*)&W2p, (void*)&Y,
                     (void*)&h_buf, (void*)&v_buf, (void*)&out, (void*)&cnt };
    hipLaunchCooperativeKernel(reinterpret_cast<void*>(ulstm_rec),
                               dim3(GBLK), dim3(256), args, 0, stream);
}

// Round 2
// 23243.655 us; speedup vs baseline: 1.1700x; 1.1700x over previous
//
#include <hip/hip_runtime.h>

// ULSTM layer: S=1024, B=32, IN=1024, H=1024
//  R2: flag-array grid barrier (no serialized RMW) + Y relayout/LDS-prefetch.

typedef unsigned short u16;
typedef __attribute__((ext_vector_type(4))) float f32x4;
typedef __attribute__((ext_vector_type(8))) short s16x8;     // 8 bf16 (MFMA A/B frag)
typedef __attribute__((ext_vector_type(8))) unsigned short u16x8;

#define SEQ   1024
#define BATCH 32
#define HDIM  1024
#define GBLK  64          // persistent blocks; each owns 16 hidden cols

__device__ __forceinline__ u16 f2bf(float f) {
    unsigned u = __builtin_bit_cast(unsigned, f);
    return (u16)((u + 0x7FFFu + ((u >> 16) & 1u)) >> 16);   // RNE
}
__device__ __forceinline__ float bf2f(u16 h) {
    return __builtin_bit_cast(float, (unsigned)h << 16);
}

// ---------------------------------------------------------------- prep kernels
// permuted column p: g = p/80, r = p%80, gate = r>>4 (0..4 = i,o,z,f,u), j = r&15
// hidden index n = 16g + j; original 5H col = gate<4 ? gate*H+n : 4H+n
__global__ void prep_w0(const float* __restrict__ W, const float* __restrict__ b_ux,
                        const float* __restrict__ b_h, const float* __restrict__ b_um,
                        u16* __restrict__ W0p, float* __restrict__ biasp) {
    int p = blockIdx.x;                       // 5120
    int g = p / 80, r = p % 80, gate = r >> 4, j = r & 15;
    int n = 16 * g + j;
    int c = (gate < 4) ? gate * 1024 + n : 4096 + n;
    for (int k = threadIdx.x; k < 1024; k += 256)
        W0p[(long)p * 1024 + k] = f2bf(W[(long)k * 5120 + c]);
    if (threadIdx.x == 0)
        biasp[p] = b_ux[c] + ((gate < 4) ? b_h[gate * 1024 + n] : b_um[n]);
}

__global__ void prep_w1(const float* __restrict__ W, u16* __restrict__ W1p) {
    int qq = blockIdx.x;                      // 4096
    int g = qq >> 6, r = qq & 63, gate = r >> 4, j = r & 15;
    int n = 16 * g + j;
    int c = gate * 1024 + n;
    for (int k = threadIdx.x; k < 1024; k += 256)
        W1p[(long)qq * 1024 + k] = f2bf(W[(long)k * 4096 + c]);
}

__global__ void prep_w2(const float* __restrict__ W, u16* __restrict__ W2p) {
    int n = blockIdx.x;                       // 1024
    for (int k = threadIdx.x; k < 1024; k += 256)
        W2p[(long)n * 1024 + k] = f2bf(W[(long)k * 1024 + n]);
}

// ---------------------------------------------------------- input projection
// C = X(32768x1024) @ W0p^T, + biasp; output re-laid out per (g,t) slice:
// Yp[(((g*1024 + s)*32 + b)*80 + r] so ulstm_rec block g reads a contiguous
// 5120B slice per timestep.
__global__ void __launch_bounds__(256) gemm_in(const float* __restrict__ X,
                                               const u16* __restrict__ W0p,
                                               const float* __restrict__ biasp,
                                               u16* __restrict__ Yp) {
    __shared__ u16 As[128 * 40];
    __shared__ u16 Bs[64 * 40];
    const int tid = threadIdx.x, lane = tid & 63, w = tid >> 6;
    const int m = lane & 15, q = lane >> 4;
    const int m0 = blockIdx.y * 128, n0 = blockIdx.x * 64;

    f32x4 acc[2][4];
#pragma unroll
    for (int a = 0; a < 2; ++a)
#pragma unroll
        for (int b = 0; b < 4; ++b) acc[a][b] = (f32x4){0.f, 0.f, 0.f, 0.f};

    const int ar = tid >> 1, as = (tid & 1) * 16;
    const int br = tid >> 2, bs = (tid & 3) * 8;

    for (int k0 = 0; k0 < 1024; k0 += 32) {
        const float* xp = X + (long)(m0 + ar) * 1024 + k0 + as;
        float4 x0 = *(const float4*)(xp);
        float4 x1 = *(const float4*)(xp + 4);
        float4 x2 = *(const float4*)(xp + 8);
        float4 x3 = *(const float4*)(xp + 12);
        u16x8 pa, pb;
        pa[0]=f2bf(x0.x); pa[1]=f2bf(x0.y); pa[2]=f2bf(x0.z); pa[3]=f2bf(x0.w);
        pa[4]=f2bf(x1.x); pa[5]=f2bf(x1.y); pa[6]=f2bf(x1.z); pa[7]=f2bf(x1.w);
        pb[0]=f2bf(x2.x); pb[1]=f2bf(x2.y); pb[2]=f2bf(x2.z); pb[3]=f2bf(x2.w);
        pb[4]=f2bf(x3.x); pb[5]=f2bf(x3.y); pb[6]=f2bf(x3.z); pb[7]=f2bf(x3.w);
        u16x8 bv = *(const u16x8*)(W0p + (long)(n0 + br) * 1024 + k0 + bs);

        *(u16x8*)&As[ar * 40 + as]     = pa;
        *(u16x8*)&As[ar * 40 + as + 8] = pb;
        *(u16x8*)&Bs[br * 40 + bs]     = bv;
        __syncthreads();

        s16x8 a0 = *(const s16x8*)&As[(w * 32 + m) * 40 + q * 8];
        s16x8 a1 = *(const s16x8*)&As[(w * 32 + 16 + m) * 40 + q * 8];
#pragma unroll
        for (int nt = 0; nt < 4; ++nt) {
            s16x8 b = *(const s16x8*)&Bs[(nt * 16 + m) * 40 + q * 8];
            acc[0][nt] = __builtin_amdgcn_mfma_f32_16x16x32_bf16(a0, b, acc[0][nt], 0, 0, 0);
            acc[1][nt] = __builtin_amdgcn_mfma_f32_16x16x32_bf16(a1, b, acc[1][nt], 0, 0, 0);
        }
        __syncthreads();
    }
#pragma unroll
    for (int mt = 0; mt < 2; ++mt)
#pragma unroll
        for (int nt = 0; nt < 4; ++nt) {
            int p = n0 + nt * 16 + m;
            int gg = p / 80, rr = p - gg * 80;
            float bias = biasp[p];
#pragma unroll
            for (int r = 0; r < 4; ++r) {
                int row = m0 + w * 32 + mt * 16 + q * 4 + r;
                int s = row >> 5, b = row & 31;
                Yp[(((long)gg * 1024 + s) * 32 + b) * 80 + rr] = f2bf(acc[mt][nt][r] + bias);
            }
        }
}

// -------------------------------------------------------------- grid barrier
// flags: 64 slots, 128B apart. Arrival = own-flag release store (parallel
// across blocks, no same-line RMW). Wait = wave0's 64 lanes poll all flags
// in parallel + ballot. One acquire fence on exit.
__device__ __forceinline__ void gridbar(unsigned* flags, unsigned phase, int g) {
    __syncthreads();
    if (threadIdx.x < 64) {
        if (threadIdx.x == 0)
            __hip_atomic_store(&flags[g * 32], phase, __ATOMIC_RELEASE,
                               __HIP_MEMORY_SCOPE_AGENT);
        unsigned v;
        do {
            v = __hip_atomic_load(&flags[threadIdx.x * 32], __ATOMIC_RELAXED,
                                  __HIP_MEMORY_SCOPE_AGENT);
        } while (__ballot(v >= phase) != ~0ull);
        __builtin_amdgcn_fence(__ATOMIC_ACQUIRE, "agent");
    }
    __syncthreads();
}

// ------------------------------------------------------------- recurrence
__global__ void __launch_bounds__(256) ulstm_rec(const u16* __restrict__ W1p,
                                                 const u16* __restrict__ W2p,
                                                 const u16* __restrict__ Yp,
                                                 u16* h_buf, u16* v_buf,
                                                 float* __restrict__ out,
                                                 unsigned* flags) {
    __shared__ u16 stage[32 * 1032];        // h (phase A) / v (phase B)
    __shared__ u16 ys[2][2560];             // double-buffered Y slice (32x80)
    __shared__ float gl[4][32][17];         // i,o,z,f (padded)
    __shared__ float c_l[32][17], ct_l[32][17];

    const int g = blockIdx.x, tid = threadIdx.x, lane = tid & 63, w = tid >> 6;
    const int m = lane & 15, q = lane >> 4;

    for (int i = tid; i < 512; i += 256) {
        int row = i >> 4, col = i & 15;
        c_l[row][col] = 0.f; ct_l[row][col] = 0.f;
        h_buf[row * 1024 + g * 16 + col] = 0;
    }
    {   // prefetch Y slice for t=0
        const u16* src = Yp + (long)g * 1024 * 2560;
        for (int i = tid; i < 320; i += 256)
            *(u16x8*)&ys[0][i * 8] = *(const u16x8*)&src[i * 8];
    }
    unsigned phase = 1;
    gridbar(flags, phase, g);

    for (int t = 0; t < SEQ; ++t) {
        const u16* ysb = ys[t & 1];
        // ---- stage h into LDS (critical path: issue first)
        for (int cch = tid; cch < 4096; cch += 256) {
            int r = cch >> 7, kc = cch & 127;
            *(u16x8*)&stage[r * 1032 + kc * 8] = *(const u16x8*)&h_buf[r * 1024 + kc * 8];
        }
        // ---- prefetch Y slice t+1 (off critical path, hides HBM latency)
        if (t + 1 < SEQ) {
            const u16* src = Yp + ((long)g * 1024 + t + 1) * 2560;
            u16* dst = ys[(t + 1) & 1];
            for (int i = tid; i < 320; i += 256)
                *(u16x8*)&dst[i * 8] = *(const u16x8*)&src[i * 8];
        }
        __syncthreads();

        // ---- gemm1: preact[32 x 16] for gate w
        f32x4 acc0 = (f32x4){0.f,0.f,0.f,0.f}, acc1 = (f32x4){0.f,0.f,0.f,0.f};
        {
            const int brow = g * 64 + w * 16 + m;
            const u16* wp = W1p + (long)brow * 1024;
#pragma unroll 4
            for (int kc = 0; kc < 32; ++kc) {
                int k0 = kc * 32 + q * 8;
                s16x8 a0 = *(const s16x8*)&stage[m * 1032 + k0];
                s16x8 a1 = *(const s16x8*)&stage[(16 + m) * 1032 + k0];
                s16x8 b  = *(const s16x8*)&wp[k0];
                acc0 = __builtin_amdgcn_mfma_f32_16x16x32_bf16(a0, b, acc0, 0, 0, 0);
                acc1 = __builtin_amdgcn_mfma_f32_16x16x32_bf16(a1, b, acc1, 0, 0, 0);
            }
        }
#pragma unroll
        for (int r = 0; r < 4; ++r) {
            int row0 = q * 4 + r, row1 = row0 + 16;
            float p0 = acc0[r] + bf2f(ysb[row0 * 80 + w * 16 + m]);
            float p1 = acc1[r] + bf2f(ysb[row1 * 80 + w * 16 + m]);
            float g0 = 1.f / (1.f + __expf(-p0));
            float g1 = 1.f / (1.f + __expf(-p1));
            gl[w][row0][m] = g0;
            gl[w][row1][m] = g1;
            if (w == 2) {       // z-gate: publish v = sigmoid(z) * tanh(c_prev)
                v_buf[row0 * 1024 + g * 16 + m] = f2bf(g0 * ct_l[row0][m]);
                v_buf[row1 * 1024 + g * 16 + m] = f2bf(g1 * ct_l[row1][m]);
            }
        }
        gridbar(flags, ++phase, g);         // v published grid-wide

        // ---- stage v into LDS
        for (int cch = tid; cch < 4096; cch += 256) {
            int r = cch >> 7, kc = cch & 127;
            *(u16x8*)&stage[r * 1032 + kc * 8] = *(const u16x8*)&v_buf[r * 1024 + kc * 8];
        }
        __syncthreads();

        // ---- gemm2 + state update (waves 0,1)
        if (w < 2) {
            f32x4 acc = (f32x4){0.f,0.f,0.f,0.f};
            const u16* wp = W2p + (long)(g * 16 + m) * 1024;
#pragma unroll 4
            for (int kc = 0; kc < 32; ++kc) {
                int k0 = kc * 32 + q * 8;
                s16x8 a = *(const s16x8*)&stage[(w * 16 + m) * 1032 + k0];
                s16x8 b = *(const s16x8*)&wp[k0];
                acc = __builtin_amdgcn_mfma_f32_16x16x32_bf16(a, b, acc, 0, 0, 0);
            }
#pragma unroll
            for (int r = 0; r < 4; ++r) {
                int row = w * 16 + q * 4 + r;
                float up = acc[r] + bf2f(ysb[row * 80 + 64 + m]);
                float eu = __expf(2.f * up);
                float u = 1.f - 2.f / (eu + 1.f);           // tanh
                float iv = gl[0][row][m], ov = gl[1][row][m], fv = gl[3][row][m];
                float cv = c_l[row][m];
                float cn = iv * u + fv * cv;
                float ec = __expf(2.f * cn);
                float ctn = 1.f - 2.f / (ec + 1.f);
                float hn = ov * ctn;
                c_l[row][m] = cn;
                ct_l[row][m] = ctn;
                h_buf[row * 1024 + g * 16 + m] = f2bf(hn);
                out[(long)(t * 32 + row) * 1024 + g * 16 + m] = hn;
                if (t == SEQ - 1) {
                    out[33554432l + row * 1024 + g * 16 + m] = hn;          // h_n
                    out[33554432l + 32768 + row * 1024 + g * 16 + m] = cn;  // c_n
                }
            }
        }
        gridbar(flags, ++phase, g);         // h published grid-wide
    }
}

// ---------------------------------------------------------------------- host
extern "C" void kernel_launch(void* const* d_in, const int* in_sizes, int n_in,
                              void* d_out, int out_size, void* d_ws, size_t ws_size,
                              hipStream_t stream) {
    (void)in_sizes; (void)n_in; (void)out_size; (void)ws_size;
    const float* X  = (const float*)d_in[0];
    const float* W0 = (const float*)d_in[1];
    const float* b0 = (const float*)d_in[2];
    const float* W1 = (const float*)d_in[3];
    const float* b1 = (const float*)d_in[4];
    const float* W2 = (const float*)d_in[5];
    const float* b2 = (const float*)d_in[6];
    float* out = (float*)d_out;
    char* ws = (char*)d_ws;

    u16*   Yp    = (u16*)(ws);                      // 335,544,320 B
    u16*   W0p   = (u16*)(ws + 335544320l);         // 10,485,760
    u16*   W1p   = (u16*)(ws + 346030080l);         // 8,388,608
    u16*   W2p   = (u16*)(ws + 354418688l);         // 2,097,152
    float* biasp = (float*)(ws + 356515840l);       // 20,480
    u16*   h_buf = (u16*)(ws + 356536320l);         // 65,536
    u16*   v_buf = (u16*)(ws + 356601856l);         // 65,536
    unsigned* flags = (unsigned*)(ws + 356667392l); // 8,192 (64 x 128B)

    hipMemsetAsync(flags, 0, 8192, stream);
    prep_w0<<<5120, 256, 0, stream>>>(W0, b0, b1, b2, W0p, biasp);
    prep_w1<<<4096, 256, 0, stream>>>(W1, W1p);
    prep_w2<<<1024, 256, 0, stream>>>(W2, W2p);
    gemm_in<<<dim3(80, 256), 256, 0, stream>>>(X, W0p, biasp, Yp);

    void* args[] = { (void*)&W1p, (void*)&W2p, (void*)&Yp,
                     (void*)&h_buf, (void*)&v_buf, (void*)&out, (void*)&flags };
    hipLaunchCooperativeKernel(reinterpret_cast<void*>(ulstm_rec),
                               dim3(GBLK), dim3(256), args, 0, stream);
}